// Round 1
// baseline (320.885 us; speedup 1.0000x reference)
//
#include <hip/hip_runtime.h>

namespace {
constexpr int nB  = 32;
constexpr int nLC = 2048;
constexpr int nLQ = 128;
constexpr int nD  = 128;

constexpr int TM1 = 64;           // k1 rows per block
constexpr int NT1 = nLC / TM1;    // 32 tiles
constexpr int RS  = 8;            // k3 row splits
constexpr int ROWS3 = nLC / RS;   // 256 rows per k3 block
constexpr int CH3 = 16;           // k3 chunk rows
constexpr int TM2 = 64;           // k4 rows per block
constexpr int NT2 = nLC / TM2;    // 32

// workspace layout (floats)
constexpr size_t WS_S    = 0;                                   // B*LC*LQ
constexpr size_t WS_CMAX = WS_S    + (size_t)nB*nLC*nLQ;        // B*NT1*LQ
constexpr size_t WS_TNP  = WS_CMAX + (size_t)nB*NT1*nLQ;        // B*RS*LQ*D
constexpr size_t WS_ZP   = WS_TNP  + (size_t)nB*RS*nLQ*nD;      // B*RS*LQ
constexpr size_t WS_TN   = WS_ZP   + (size_t)nB*RS*nLQ;         // B*LQ*D
constexpr size_t WS_Z    = WS_TN   + (size_t)nB*nLQ*nD;         // B*LQ
} // namespace

// ---------------------------------------------------------------------------
// k1: S[b,i,j] = (C@w1)[i] + (Q@w2)[j] + sum_d C[i,d]*w3[d]*Q[j,d]
//     also per-tile column max over i (rows with cmask==1 excluded)
// ---------------------------------------------------------------------------
__global__ __launch_bounds__(256) void k1_scores(
    const float* __restrict__ C, const float* __restrict__ Q,
    const float* __restrict__ cmask, const float* __restrict__ w,
    float* __restrict__ ws)
{
  const int t  = threadIdx.x;
  const int b  = blockIdx.y;
  const int i0 = blockIdx.x * TM1;

  float* __restrict__ Sg    = ws + WS_S;
  float* __restrict__ cmaxp = ws + WS_CMAX;

  __shared__ float wl[3*nD];
  __shared__ float Cs[TM1][68];    // raw C chunk (64 rows x 64 k)
  __shared__ float Qs[nLQ][68];    // Q*w3 chunk (128 rows x 64 k)
  __shared__ float cw1l[TM1];
  __shared__ float qw2l[nLQ];
  __shared__ float cml[TM1];
  __shared__ float redbuf[16][nLQ];

  for (int idx = t; idx < 3*nD; idx += 256) wl[idx] = w[idx];
  if (t < TM1) cml[t] = cmask[b*nLC + i0 + t];
  __syncthreads();

  // qw2 (threads 0..127, one Q row each)
  if (t < nLQ) {
    const float4* qr = (const float4*)(Q + ((size_t)b*nLQ + t)*nD);
    float acc = 0.f;
    #pragma unroll 8
    for (int k4 = 0; k4 < 32; ++k4) {
      float4 v = qr[k4];
      acc += v.x*wl[nD+k4*4+0] + v.y*wl[nD+k4*4+1]
           + v.z*wl[nD+k4*4+2] + v.w*wl[nD+k4*4+3];
    }
    qw2l[t] = acc;
  }

  const int ty = t >> 4, tx = t & 15;
  const int r0 = ty * 4;
  float acc[4][8];
  #pragma unroll
  for (int i = 0; i < 4; ++i) {
    #pragma unroll
    for (int j = 0; j < 8; ++j) acc[i][j] = 0.f;
  }
  float cw1acc = 0.f;

  for (int kc = 0; kc < 2; ++kc) {
    __syncthreads();
    {
      const int row = t >> 2, k0 = (t & 3) * 16;
      const float4* src = (const float4*)(C + ((size_t)b*nLC + i0 + row)*nD + kc*64 + k0);
      float4* dst = (float4*)(&Cs[row][k0]);
      #pragma unroll
      for (int u = 0; u < 4; ++u) dst[u] = src[u];
    }
    {
      const int j = t >> 1, k0 = (t & 1) * 32;
      const float4* src = (const float4*)(Q + ((size_t)b*nLQ + j)*nD + kc*64 + k0);
      #pragma unroll
      for (int u = 0; u < 8; ++u) {
        float4 v = src[u];
        const int kk = k0 + u*4;
        v.x *= wl[2*nD + kc*64 + kk + 0];
        v.y *= wl[2*nD + kc*64 + kk + 1];
        v.z *= wl[2*nD + kc*64 + kk + 2];
        v.w *= wl[2*nD + kc*64 + kk + 3];
        *(float4*)(&Qs[j][kk]) = v;
      }
    }
    __syncthreads();
    if (t < TM1) {
      float a = 0.f;
      for (int k = 0; k < 64; ++k) a += Cs[t][k] * wl[kc*64 + k];
      cw1acc += a;
    }
    for (int k = 0; k < 64; k += 4) {
      float4 a4[4], b4[8];
      #pragma unroll
      for (int i = 0; i < 4; ++i) a4[i] = *(const float4*)(&Cs[r0+i][k]);
      #pragma unroll
      for (int j = 0; j < 8; ++j) b4[j] = *(const float4*)(&Qs[tx + j*16][k]);
      #pragma unroll
      for (int i = 0; i < 4; ++i) {
        #pragma unroll
        for (int j = 0; j < 8; ++j) {
          acc[i][j] += a4[i].x*b4[j].x;
          acc[i][j] += a4[i].y*b4[j].y;
          acc[i][j] += a4[i].z*b4[j].z;
          acc[i][j] += a4[i].w*b4[j].w;
        }
      }
    }
  }

  if (t < TM1) cw1l[t] = cw1acc;
  __syncthreads();

  float colv[8];
  #pragma unroll
  for (int j = 0; j < 8; ++j) colv[j] = -3.0e38f;
  #pragma unroll
  for (int i = 0; i < 4; ++i) {
    const int gi = i0 + r0 + i;
    const float cw = cw1l[r0 + i];
    const bool cm = (cml[r0 + i] != 0.0f);
    float* srow = Sg + ((size_t)b*nLC + gi)*nLQ;
    #pragma unroll
    for (int j = 0; j < 8; ++j) {
      const int c = tx + j*16;
      const float v = acc[i][j] + cw + qw2l[c];
      srow[c] = v;
      if (!cm) colv[j] = fmaxf(colv[j], v);
    }
  }
  #pragma unroll
  for (int j = 0; j < 8; ++j) redbuf[ty][tx + j*16] = colv[j];
  __syncthreads();
  if (t < nLQ) {
    float m = -3.0e38f;
    #pragma unroll
    for (int yy = 0; yy < 16; ++yy) m = fmaxf(m, redbuf[yy][t]);
    cmaxp[((size_t)b*NT1 + blockIdx.x)*nLQ + t] = m;
  }
}

// ---------------------------------------------------------------------------
// k3: per (b, row-split): Tn_partial[j,d] = sum_i exp(S[i,j]-M[j])*C[i,d]
//     Z_partial[j] = sum_i exp(S[i,j]-M[j])  (cmask rows contribute 0)
// ---------------------------------------------------------------------------
__global__ __launch_bounds__(256) void k3_colsum(
    const float* __restrict__ C, const float* __restrict__ cmask,
    float* __restrict__ ws)
{
  const int t  = threadIdx.x;
  const int b  = blockIdx.y;
  const int rs = blockIdx.x;
  const int i0 = rs * ROWS3;

  const float* __restrict__ Sg    = ws + WS_S;
  const float* __restrict__ cmaxp = ws + WS_CMAX;
  float* __restrict__ Tnp = ws + WS_TNP;
  float* __restrict__ Zp  = ws + WS_ZP;

  __shared__ float Mlds[nLQ];
  __shared__ float Cch[CH3][132];
  __shared__ float Ech[CH3][132];

  if (t < nLQ) {
    float m = -3.0e38f;
    for (int tt = 0; tt < NT1; ++tt)
      m = fmaxf(m, cmaxp[((size_t)b*NT1 + tt)*nLQ + t]);
    Mlds[t] = m;
  }

  const int dg = t & 15, jg = t >> 4;
  const int d0 = dg*8, jl0 = jg*8;
  float accT[8][8];
  float z[8];
  #pragma unroll
  for (int a = 0; a < 8; ++a) {
    z[a] = 0.f;
    #pragma unroll
    for (int u = 0; u < 8; ++u) accT[a][u] = 0.f;
  }

  for (int ch = 0; ch < ROWS3/CH3; ++ch) {
    __syncthreads();
    const int row = t >> 4, c0 = (t & 15)*8;
    const int gi = i0 + ch*CH3 + row;
    {
      const float4* src = (const float4*)(C + ((size_t)b*nLC + gi)*nD + c0);
      *(float4*)(&Cch[row][c0])   = src[0];
      *(float4*)(&Cch[row][c0+4]) = src[1];
    }
    {
      const float cmv = cmask[b*nLC + gi];
      const float4* src = (const float4*)(Sg + ((size_t)b*nLC + gi)*nLQ + c0);
      float4 s0 = src[0], s1 = src[1];
      float e[8];
      if (cmv != 0.0f) {
        #pragma unroll
        for (int u = 0; u < 8; ++u) e[u] = 0.f;
      } else {
        e[0] = __expf(s0.x - Mlds[c0+0]);
        e[1] = __expf(s0.y - Mlds[c0+1]);
        e[2] = __expf(s0.z - Mlds[c0+2]);
        e[3] = __expf(s0.w - Mlds[c0+3]);
        e[4] = __expf(s1.x - Mlds[c0+4]);
        e[5] = __expf(s1.y - Mlds[c0+5]);
        e[6] = __expf(s1.z - Mlds[c0+6]);
        e[7] = __expf(s1.w - Mlds[c0+7]);
      }
      *(float4*)(&Ech[row][c0])   = make_float4(e[0],e[1],e[2],e[3]);
      *(float4*)(&Ech[row][c0+4]) = make_float4(e[4],e[5],e[6],e[7]);
    }
    __syncthreads();
    for (int i = 0; i < CH3; ++i) {
      float4 e0 = *(const float4*)(&Ech[i][jl0]);
      float4 e1 = *(const float4*)(&Ech[i][jl0+4]);
      float4 cv0 = *(const float4*)(&Cch[i][d0]);
      float4 cv1 = *(const float4*)(&Cch[i][d0+4]);
      float ev[8] = {e0.x,e0.y,e0.z,e0.w,e1.x,e1.y,e1.z,e1.w};
      float cv[8] = {cv0.x,cv0.y,cv0.z,cv0.w,cv1.x,cv1.y,cv1.z,cv1.w};
      #pragma unroll
      for (int a = 0; a < 8; ++a) {
        z[a] += ev[a];
        #pragma unroll
        for (int u = 0; u < 8; ++u) accT[a][u] += ev[a]*cv[u];
      }
    }
  }

  #pragma unroll
  for (int a = 0; a < 8; ++a) {
    float* dst = Tnp + (((size_t)b*RS + rs)*nLQ + jl0 + a)*nD + d0;
    *(float4*)(dst)     = make_float4(accT[a][0],accT[a][1],accT[a][2],accT[a][3]);
    *(float4*)(dst + 4) = make_float4(accT[a][4],accT[a][5],accT[a][6],accT[a][7]);
  }
  if (dg == 0) {
    #pragma unroll
    for (int a = 0; a < 8; ++a)
      Zp[((size_t)b*RS + rs)*nLQ + jl0 + a] = z[a];
  }
}

// ---------------------------------------------------------------------------
// k3b: reduce partials: Tn = sum_rs Tnp ; Z = sum_rs Zp
// ---------------------------------------------------------------------------
__global__ __launch_bounds__(256) void k3b_reduce(float* __restrict__ ws)
{
  const size_t TN_ELEMS = (size_t)nB*nLQ*nD;
  const size_t gid = (size_t)blockIdx.x*256 + threadIdx.x;
  if (gid < TN_ELEMS) {
    const size_t bb = gid / (nLQ*nD);
    const size_t rest = gid % (nLQ*nD);
    const float* src = ws + WS_TNP + bb*(size_t)RS*nLQ*nD + rest;
    float s = 0.f;
    #pragma unroll
    for (int r = 0; r < RS; ++r) s += src[(size_t)r*nLQ*nD];
    ws[WS_TN + gid] = s;
  } else {
    const size_t zid = gid - TN_ELEMS;
    if (zid < (size_t)nB*nLQ) {
      const size_t bb = zid / nLQ;
      const size_t j  = zid % nLQ;
      const float* src = ws + WS_ZP + bb*(size_t)RS*nLQ + j;
      float s = 0.f;
      #pragma unroll
      for (int r = 0; r < RS; ++r) s += src[r*nLQ];
      ws[WS_Z + zid] = s;
    }
  }
}

// ---------------------------------------------------------------------------
// k4: row softmax (qmask) -> S1; A = S1@Q ; Bt = (S1/Z)@Tn ;
//     out = [C, A, C*A, C*Bt]
// ---------------------------------------------------------------------------
__global__ __launch_bounds__(256) void k4_output(
    const float* __restrict__ C, const float* __restrict__ Q,
    const float* __restrict__ qmask, const float* __restrict__ ws,
    float* __restrict__ out)
{
  const int t  = threadIdx.x;
  const int b  = blockIdx.y;
  const int i0 = blockIdx.x * TM2;

  const float* __restrict__ Sg = ws + WS_S;
  const float* __restrict__ Tn = ws + WS_TN;
  const float* __restrict__ Zg = ws + WS_Z;

  __shared__ float S1l[TM2][132];
  __shared__ float Qch[16][132];
  __shared__ float Tch[16][132];
  __shared__ float Zinv[nLQ];
  __shared__ float qml[nLQ];

  if (t < nLQ) {
    qml[t]  = qmask[b*nLQ + t];
    Zinv[t] = 1.0f / Zg[b*nLQ + t];
  }
  __syncthreads();

  // ---- phase A: row softmax over j (4 lanes per row) ----
  {
    const int r = t >> 2, q = t & 3;
    const float* srow = Sg + ((size_t)b*nLC + i0 + r)*nLQ + q*32;
    float v[32], msk[32];
    #pragma unroll
    for (int u4 = 0; u4 < 8; ++u4) {
      float4 vv = ((const float4*)srow)[u4];
      v[u4*4+0] = vv.x; v[u4*4+1] = vv.y; v[u4*4+2] = vv.z; v[u4*4+3] = vv.w;
    }
    #pragma unroll
    for (int u = 0; u < 32; ++u) msk[u] = qml[q*32 + u];
    float m = -3.0e38f;
    #pragma unroll
    for (int u = 0; u < 32; ++u) { if (msk[u] == 0.0f) m = fmaxf(m, v[u]); }
    m = fmaxf(m, __shfl_xor(m, 1));
    m = fmaxf(m, __shfl_xor(m, 2));
    float ssum = 0.0f;
    float p[32];
    #pragma unroll
    for (int u = 0; u < 32; ++u) {
      p[u] = (msk[u] != 0.0f) ? 0.0f : __expf(v[u] - m);
      ssum += p[u];
    }
    ssum += __shfl_xor(ssum, 1);
    ssum += __shfl_xor(ssum, 2);
    const float inv = 1.0f / ssum;
    #pragma unroll
    for (int u4 = 0; u4 < 8; ++u4) {
      float4 o = make_float4(p[u4*4+0]*inv, p[u4*4+1]*inv,
                             p[u4*4+2]*inv, p[u4*4+3]*inv);
      *(float4*)(&S1l[r][q*32 + u4*4]) = o;
    }
  }

  float accA[4][8], accB[4][8];
  #pragma unroll
  for (int i = 0; i < 4; ++i) {
    #pragma unroll
    for (int u = 0; u < 8; ++u) { accA[i][u] = 0.f; accB[i][u] = 0.f; }
  }
  const int rg = t >> 4, dg = t & 15;
  const int r0 = rg*4, d0 = dg*8;

  // ---- phase B: A += S1*Q ; Bt += (S1/Z)*Tn, j-chunks of 16 ----
  for (int jc = 0; jc < nLQ/16; ++jc) {
    __syncthreads();
    {
      const int jj = t >> 4, ds = (t & 15)*8;
      const int j  = jc*16 + jj;
      const float4* qs = (const float4*)(Q + ((size_t)b*nLQ + j)*nD + ds);
      *(float4*)(&Qch[jj][ds])   = qs[0];
      *(float4*)(&Qch[jj][ds+4]) = qs[1];
      const float4* tsv = (const float4*)(Tn + ((size_t)b*nLQ + j)*nD + ds);
      *(float4*)(&Tch[jj][ds])   = tsv[0];
      *(float4*)(&Tch[jj][ds+4]) = tsv[1];
    }
    __syncthreads();
    for (int jj2 = 0; jj2 < 16; ++jj2) {
      const int j = jc*16 + jj2;
      const float zf = Zinv[j];
      float4 q0 = *(const float4*)(&Qch[jj2][d0]);
      float4 q1 = *(const float4*)(&Qch[jj2][d0+4]);
      float4 t0 = *(const float4*)(&Tch[jj2][d0]);
      float4 t1 = *(const float4*)(&Tch[jj2][d0+4]);
      float qv[8] = {q0.x,q0.y,q0.z,q0.w,q1.x,q1.y,q1.z,q1.w};
      float tv[8] = {t0.x,t0.y,t0.z,t0.w,t1.x,t1.y,t1.z,t1.w};
      #pragma unroll
      for (int i = 0; i < 4; ++i) {
        const float s1 = S1l[r0+i][j];
        const float c2 = s1 * zf;
        #pragma unroll
        for (int u = 0; u < 8; ++u) {
          accA[i][u] += s1 * qv[u];
          accB[i][u] += c2 * tv[u];
        }
      }
    }
  }

  // ---- epilogue: out = [C, A, C*A, C*Bt] ----
  #pragma unroll
  for (int i = 0; i < 4; ++i) {
    const int gi = i0 + r0 + i;
    const float4* cr = (const float4*)(C + ((size_t)b*nLC + gi)*nD + d0);
    float4 cA = cr[0], cB = cr[1];
    float cv[8] = {cA.x,cA.y,cA.z,cA.w,cB.x,cB.y,cB.z,cB.w};
    float* orow = out + ((size_t)b*nLC + gi)*(4*nD);

    *(float4*)(orow + d0)     = cA;
    *(float4*)(orow + d0 + 4) = cB;

    *(float4*)(orow + nD + d0)
      = make_float4(accA[i][0],accA[i][1],accA[i][2],accA[i][3]);
    *(float4*)(orow + nD + d0 + 4)
      = make_float4(accA[i][4],accA[i][5],accA[i][6],accA[i][7]);

    *(float4*)(orow + 2*nD + d0)
      = make_float4(cv[0]*accA[i][0],cv[1]*accA[i][1],cv[2]*accA[i][2],cv[3]*accA[i][3]);
    *(float4*)(orow + 2*nD + d0 + 4)
      = make_float4(cv[4]*accA[i][4],cv[5]*accA[i][5],cv[6]*accA[i][6],cv[7]*accA[i][7]);

    *(float4*)(orow + 3*nD + d0)
      = make_float4(cv[0]*accB[i][0],cv[1]*accB[i][1],cv[2]*accB[i][2],cv[3]*accB[i][3]);
    *(float4*)(orow + 3*nD + d0 + 4)
      = make_float4(cv[4]*accB[i][4],cv[5]*accB[i][5],cv[6]*accB[i][6],cv[7]*accB[i][7]);
  }
}

// ---------------------------------------------------------------------------
extern "C" void kernel_launch(void* const* d_in, const int* in_sizes, int n_in,
                              void* d_out, int out_size, void* d_ws, size_t ws_size,
                              hipStream_t stream)
{
  const float* C     = (const float*)d_in[0];
  const float* Q     = (const float*)d_in[1];
  const float* cmask = (const float*)d_in[2];
  const float* qmask = (const float*)d_in[3];
  const float* w     = (const float*)d_in[4];
  float* out = (float*)d_out;
  float* ws  = (float*)d_ws;

  k1_scores<<<dim3(NT1, nB), 256, 0, stream>>>(C, Q, cmask, w, ws);
  k3_colsum<<<dim3(RS, nB), 256, 0, stream>>>(C, cmask, ws);
  {
    const int total = nB*nLQ*nD + nB*nLQ;           // 528384
    k3b_reduce<<<dim3((total + 255)/256), 256, 0, stream>>>(ws);
  }
  k4_output<<<dim3(NT2, nB), 256, 0, stream>>>(C, Q, qmask, ws, out);
}